// Round 5
// baseline (135.770 us; speedup 1.0000x reference)
//
#include <hip/hip_runtime.h>

#define L_LEN   16384
#define P_DIM   512
#define CHUNK   32
#define NCHUNK  512        // L_LEN / CHUNK

#define KDIM    1024       // 2*P, re/im interleaved: k = 2p (re), 2p+1 (im)
#define NDIM    512
#define BM      64         // time rows per fused block
#define NBLK    (L_LEN / BM)   // 256 fused blocks = 1/CU

typedef __bf16 bf16_t;
typedef __bf16 bf16x8 __attribute__((ext_vector_type(8)));
typedef float  floatx4 __attribute__((ext_vector_type(4)));

__device__ __forceinline__ uint32_t pack_bf16(float a, float b) {
    bf16_t ha = (bf16_t)a, hb = (bf16_t)b;
    return (uint32_t)__builtin_bit_cast(unsigned short, ha)
         | ((uint32_t)__builtin_bit_cast(unsigned short, hb) << 16);
}

// Per-channel discretization constants: a = exp(lambda*step), B = (a-1)/lambda
__device__ __forceinline__ void ch_consts(float lam0, float lam1, float ls,
                                          float& ar, float& ai,
                                          float& br, float& bi) {
    float lr = -expf(lam0);               // Re(lambda) < 0
    float li = lam1;                      // Im(lambda)
    float s  = expf(ls);
    float er = expf(lr * s);
    ar = er * cosf(li * s);
    ai = er * sinf(li * s);
    float dr = ar - 1.0f, di = ai;
    float inv = 1.0f / (lr * lr + li * li);
    br = (dr * lr + di * li) * inv;
    bi = (di * lr - dr * li) * inv;
}

// Phase 1: per (chunk, channel-pair) local scan, zero init; write end states.
// Thread t handles channels 2t, 2t+1 via float2 loads. Bt pack fused in.
__global__ void __launch_bounds__(256) k_scan_ends(const float* __restrict__ u,
        const float* __restrict__ Lam, const float* __restrict__ lstep,
        const float* __restrict__ Vre, const float* __restrict__ Vim,
        float2* __restrict__ endv, bf16_t* __restrict__ Bt) {
    const int t = threadIdx.x;
    const int c = blockIdx.x;

    // Bt pack: Bt[j][2p]=V_re[j][p], Bt[j][2p+1]=-V_im[j][p]. idx covers 512*512/2.
    {
        int idx = c * 256 + t;
        float2 vr = ((const float2*)Vre)[idx];
        float2 vi = ((const float2*)Vim)[idx];
        ((uint2*)Bt)[idx] = make_uint2(pack_bf16(vr.x, -vi.x),
                                       pack_bf16(vr.y, -vi.y));
    }

    float4 lam4 = ((const float4*)Lam)[t];       // channels 2t, 2t+1
    float2 ls2  = ((const float2*)lstep)[t];
    float ar0, ai0, br0, bi0, ar1, ai1, br1, bi1;
    ch_consts(lam4.x, lam4.y, ls2.x, ar0, ai0, br0, bi0);
    ch_consts(lam4.z, lam4.w, ls2.y, ar1, ai1, br1, bi1);

    float xr0 = 0.f, xi0 = 0.f, xr1 = 0.f, xi1 = 0.f;
    const float2* up = (const float2*)(u + (size_t)c * CHUNK * P_DIM) + t;
    #pragma unroll 8
    for (int k = 0; k < CHUNK; ++k) {
        float2 uv = up[(size_t)k * (P_DIM / 2)];
        float nr0 = ar0 * xr0 - ai0 * xi0 + br0 * uv.x;
        float ni0 = ar0 * xi0 + ai0 * xr0 + bi0 * uv.x;
        float nr1 = ar1 * xr1 - ai1 * xi1 + br1 * uv.y;
        float ni1 = ar1 * xi1 + ai1 * xr1 + bi1 * uv.y;
        xr0 = nr0; xi0 = ni0; xr1 = nr1; xi1 = ni1;
    }
    ((float4*)endv)[c * 256 + t] = make_float4(xr0, xi0, xr1, xi1);
}

// Phase 2: Kogge-Stone carry scan over 512 chunk aggregates.
// Block = 2 channels x 512 chunks = 1024 threads; 256 blocks.
// carry[c] = state entering chunk c; A_chunk = a^CHUNK.
__global__ void __launch_bounds__(1024) k_carry(const float* __restrict__ Lam,
        const float* __restrict__ lstep, const float2* __restrict__ endv,
        float2* __restrict__ carry) {
    __shared__ float2 zl[NCHUNK * 2];
    const int tid = threadIdx.x;
    const int g = tid & 1;            // channel slot within block
    const int c = tid >> 1;           // chunk index 0..511
    const int p = blockIdx.x * 2 + g;

    float lr = -expf(Lam[2 * p + 0]);
    float li = Lam[2 * p + 1];
    float s  = expf(lstep[p]);
    float tt = s * (float)CHUNK;
    float er = expf(lr * tt);
    float Ar = er * cosf(li * tt);    // A = a^CHUNK
    float Ai = er * sinf(li * tt);

    float2 e = endv[(size_t)c * P_DIM + p];
    float zr = e.x, zi = e.y;
    zl[c * 2 + g] = make_float2(zr, zi);
    __syncthreads();
    for (int st = 1; st < NCHUNK; st <<= 1) {
        float tr = 0.f, ti = 0.f;
        if (c >= st) { float2 v = zl[(c - st) * 2 + g]; tr = v.x; ti = v.y; }
        __syncthreads();
        zr += Ar * tr - Ai * ti;
        zi += Ar * ti + Ai * tr;
        zl[c * 2 + g] = make_float2(zr, zi);
        float nAr = Ar * Ar - Ai * Ai;    // A^(2s)
        float nAi = 2.f * Ar * Ai;
        Ar = nAr; Ai = nAi;
        __syncthreads();
    }
    float2 cv = make_float2(0.f, 0.f);
    if (c > 0) cv = zl[(c - 1) * 2 + g];   // exclusive prefix
    carry[(size_t)c * P_DIM + p] = cv;
}

// Phase 3 (fused): 64-row scan from carry directly into a 128KB LDS A-tile,
// then GEMM M=64 x N=512 x K=1024 from LDS, B-fragments direct from
// L2-resident Bt, spike-threshold epilogue. No A round-trip through HBM;
// no barriers inside the GEMM K-loop (A-LDS is read-only after one sync).
// A-LDS layout: [row][1024] bf16, XOR-swizzled at 16B-chunk granularity:
// slot (row, sc) holds chunk (row, sc ^ (row&7)) -> frag reads 2-way max.
// 128KB static LDS is gfx950-legal (m201 template precedent; 160KB/CU).
__global__ void __launch_bounds__(512, 2) k_scan_gemm(const float* __restrict__ u,
        const float* __restrict__ Lam, const float* __restrict__ lstep,
        const float2* __restrict__ carry, const bf16_t* __restrict__ Bt,
        float* __restrict__ out) {
    __shared__ bf16_t As[BM * KDIM];   // 128 KB

    const int tid = threadIdx.x;       // 0..511
    const int c   = blockIdx.x;        // time block: rows 64c .. 64c+63

    // ---- scan phase: thread = channel p, writes packed (re,im) per row ----
    {
        const int p = tid;
        float ar, ai, br, bi;
        ch_consts(Lam[2 * p + 0], Lam[2 * p + 1], lstep[p], ar, ai, br, bi);
        float2 cv = carry[(size_t)(2 * c) * P_DIM + p];   // CHUNK=32 chunk 2c
        float xr = cv.x, xi = cv.y;
        const float* up = u + (size_t)c * BM * P_DIM + p;
        const int ct  = p >> 2;          // 16B chunk within row
        const int sub = (p & 3) * 4;     // byte within chunk
        #pragma unroll 4
        for (int k = 0; k < BM; ++k) {
            float uv = up[(size_t)k * P_DIM];
            float nr = ar * xr - ai * xi + br * uv;
            float ni = ar * xi + ai * xr + bi * uv;
            xr = nr; xi = ni;
            int st = ct ^ (k & 7);
            *(uint32_t*)((char*)As + (size_t)k * 2048 + st * 16 + sub)
                = pack_bf16(xr, xi);
        }
    }
    __syncthreads();

    // ---- GEMM phase: 8 waves, each M=64 x N=64 (4x4 of 16x16x32) ----
    const int lane = tid & 63;
    const int w    = tid >> 6;        // 0..7
    const int wn   = w * 64;
    const int fr_m = lane & 15;
    const int fr_g = lane >> 4;

    floatx4 acc[4][4];
    #pragma unroll
    for (int i = 0; i < 4; ++i)
        #pragma unroll
        for (int j = 0; j < 4; ++j) {
            floatx4 z = {0.f, 0.f, 0.f, 0.f};
            acc[i][j] = z;
        }

    const bf16_t* Bw = Bt + (size_t)(wn + fr_m) * KDIM + fr_g * 8;

    #pragma unroll 2
    for (int kt = 0; kt < KDIM; kt += 32) {
        bf16x8 af[4], bf[4];
        #pragma unroll
        for (int j = 0; j < 4; ++j)
            bf[j] = *(const bf16x8*)(Bw + (size_t)j * 16 * KDIM + kt);
        #pragma unroll
        for (int i = 0; i < 4; ++i) {
            int m  = i * 16 + fr_m;
            int cc = (kt >> 3) + fr_g;
            int sc = cc ^ (m & 7);
            af[i] = *(const bf16x8*)((const char*)As + (size_t)m * 2048 + sc * 16);
        }
        #pragma unroll
        for (int i = 0; i < 4; ++i)
            #pragma unroll
            for (int j = 0; j < 4; ++j)
                acc[i][j] = __builtin_amdgcn_mfma_f32_16x16x32_bf16(
                    af[i], bf[j], acc[i][j], 0, 0, 0);
    }

    // Epilogue: C/D layout col=lane&15, row=(lane>>4)*4+reg (m89-verified).
    float* outb = out + (size_t)c * BM * NDIM;
    #pragma unroll
    for (int i = 0; i < 4; ++i)
        #pragma unroll
        for (int j = 0; j < 4; ++j)
            #pragma unroll
            for (int r = 0; r < 4; ++r) {
                int rr = i * 16 + fr_g * 4 + r;
                int cl = wn + j * 16 + fr_m;
                float v = acc[i][j][r];
                outb[(size_t)rr * NDIM + cl] = (v > 1.0f) ? 1.0f : 0.0f;
            }
}

extern "C" void kernel_launch(void* const* d_in, const int* in_sizes, int n_in,
                              void* d_out, int out_size, void* d_ws, size_t ws_size,
                              hipStream_t stream) {
    (void)in_sizes; (void)n_in; (void)out_size; (void)ws_size;
    const float* u     = (const float*)d_in[0];
    const float* Lam   = (const float*)d_in[1];
    const float* lstep = (const float*)d_in[2];
    const float* Vre   = (const float*)d_in[3];
    const float* Vim   = (const float*)d_in[4];
    float* out = (float*)d_out;

    char* ws = (char*)d_ws;
    const size_t endv_bytes  = (size_t)NCHUNK * P_DIM * sizeof(float2);   // 2 MB
    const size_t carry_bytes = endv_bytes;                                // 2 MB
    float2* endv  = (float2*)(ws);
    float2* carry = (float2*)(ws + endv_bytes);
    bf16_t* Bt    = (bf16_t*)(ws + endv_bytes + carry_bytes);             // 1 MB

    hipLaunchKernelGGL(k_scan_ends, dim3(NCHUNK), dim3(256), 0, stream,
                       u, Lam, lstep, Vre, Vim, endv, Bt);
    hipLaunchKernelGGL(k_carry, dim3(P_DIM / 2), dim3(1024), 0, stream,
                       Lam, lstep, endv, carry);
    hipLaunchKernelGGL(k_scan_gemm, dim3(NBLK), dim3(512), 0, stream,
                       u, Lam, lstep, carry, Bt, out);
}